// Round 2
// baseline (12485.672 us; speedup 1.0000x reference)
//
#include <hip/hip_runtime.h>
#include <hip/hip_bf16.h>

// ---------------- workspace layout (float offsets) ----------------
#define OFF_WN   0
#define OFF_BN   1024
#define OFF_WE   1088
#define OFF_BE   1600
#define OFF_WM   1664            // 3 * 128 * 64
#define OFF_BM   26240           // 3 * 64
#define OFF_WU   26432           // 3 * 128 * 64
#define OFF_BU   51008           // 3 * 64
#define OFF_WS1  51200           // 128 * 64
#define OFF_BS1  59392
#define OFF_BS2  59520
#define OFF_WS2  59456
#define OFF_WK1  59521           // 68 * 32
#define OFF_BK1  61697
#define OFF_WK2  61729           // 32 * 16
#define OFF_BK2  62241
#define OFF_WK3  62257
#define OFF_BK3  62273
#define OFF_TS   62274           // traffic stats (4)
#define OFF_GSUM 62278           // graph-embed accumulator (64)
#define OFF_FLAG 62344           // dtype flag: 1 = inputs are f32, 0 = bf16
#define OFF_H    65536           // h: N*64 f32, then agg: N*64 f32

__device__ __forceinline__ float bf2f(unsigned short u) {
    unsigned int i = ((unsigned int)u) << 16;
    float f;
    __builtin_memcpy(&f, &i, sizeof(f));
    return f;
}
__device__ __forceinline__ float bflo(unsigned int u) {
    unsigned int i = u << 16;
    float f; __builtin_memcpy(&f, &i, sizeof(f)); return f;
}
__device__ __forceinline__ float bfhi(unsigned int u) {
    unsigned int i = u & 0xffff0000u;
    float f; __builtin_memcpy(&f, &i, sizeof(f)); return f;
}

// ---------------- dtype sniffer: is the float data f32 or bf16? ----------------
// Reads 1024 ushorts of node_features as bf16. Genuine bf16 N(0,1) data has
// max|x| < ~10. f32 data read as bf16 has uniform-random exponent bits in the
// low halves -> max blows past 1e6 with probability 1 - ~1e-120.
__global__ void detect_dtype_kernel(const unsigned short* __restrict__ nf,
                                    int* __restrict__ flag) {
    int t = threadIdx.x;  // 64 threads
    float m = 0.f;
    for (int i = t; i < 1024; i += 64) {
        float v = fabsf(bf2f(nf[i]));
        if (!isnan(v)) m = fmaxf(m, v);
        else m = 1e30f;
    }
    for (int o = 32; o > 0; o >>= 1) m = fmaxf(m, __shfl_down(m, o));
    if (t == 0) flag[0] = (m > 1e6f) ? 1 : 0;
}

// ---------------- weight conversion: bf16/f32 -> f32 into ws ----------------
struct ConvArgs {
    const void* src[19];
    int off[19];
    int n[19];
};

__global__ __launch_bounds__(256) void convert_all_kernel(
        ConvArgs a, float* __restrict__ ws, const int* __restrict__ flagp) {
    int isf32 = *flagp;
    int ai = blockIdx.y;
    int i  = blockIdx.x * blockDim.x + threadIdx.x;
    if (i < a.n[ai]) {
        float v = isf32 ? ((const float*)a.src[ai])[i]
                        : bf2f(((const unsigned short*)a.src[ai])[i]);
        ws[a.off[ai] + i] = v;
    }
}

// ---------------- node projection: h = relu(nf @ Wn + bn) ----------------
__global__ __launch_bounds__(256) void node_proj_kernel(
        const void* __restrict__ nf, const float* __restrict__ ws,
        float* __restrict__ h, int N, const int* __restrict__ flagp) {
    int idx = blockIdx.x * blockDim.x + threadIdx.x;
    if (idx >= N * 64) return;
    int isf32 = *flagp;
    int i = idx >> 6, c = idx & 63;
    const float* Wn = ws + OFF_WN;
    float acc = ws[OFF_BN + c];
    float x[16];
    if (isf32) {
        const float* row = (const float*)nf + (size_t)i * 16;
#pragma unroll
        for (int k = 0; k < 16; ++k) x[k] = row[k];
    } else {
        const unsigned short* row = (const unsigned short*)nf + (size_t)i * 16;
#pragma unroll
        for (int k = 0; k < 16; ++k) x[k] = bf2f(row[k]);
    }
#pragma unroll
    for (int k = 0; k < 16; ++k) acc = fmaf(x[k], Wn[k * 64 + c], acc);
    h[idx] = fmaxf(acc, 0.f);
}

// ---------------- message + scatter: agg[dst] += relu([h_src, e] @ Wm + bm) ----------------
__global__ __launch_bounds__(256) void msg_kernel(
        const float* __restrict__ Wm, const float* __restrict__ bm,
        const float* __restrict__ We, const float* __restrict__ be,
        const void* __restrict__ ef,
        const int* __restrict__ src, const int* __restrict__ dst,
        const float* __restrict__ h, float* __restrict__ agg, int E,
        const int* __restrict__ flagp) {
    int isf32 = *flagp;
    int stride = gridDim.x * blockDim.x;
    for (int eidx = blockIdx.x * blockDim.x + threadIdx.x; eidx < E; eidx += stride) {
        int s = src[eidx], d = dst[eidx];
        float acc[64];
#pragma unroll
        for (int c = 0; c < 64; ++c) acc[c] = bm[c];

        // h_src part: rows 0..63 of Wm
        const float4* h4 = (const float4*)(h + (size_t)s * 64);
#pragma unroll 1
        for (int j0 = 0; j0 < 64; j0 += 8) {
            float4 xa = h4[j0 >> 2], xb = h4[(j0 >> 2) + 1];
            float x[8] = {xa.x, xa.y, xa.z, xa.w, xb.x, xb.y, xb.z, xb.w};
#pragma unroll
            for (int jj = 0; jj < 8; ++jj) {
                const float* w = Wm + (j0 + jj) * 64;
#pragma unroll
                for (int c = 0; c < 64; ++c) acc[c] = fmaf(x[jj], w[c], acc[c]);
            }
        }

        // edge part: e = relu(ef @ We + be), rows 64..127 of Wm
        float efv[8];
        if (isf32) {
            const float4* e4 = (const float4*)ef + (size_t)eidx * 2;
            float4 ra = e4[0], rb = e4[1];
            efv[0] = ra.x; efv[1] = ra.y; efv[2] = ra.z; efv[3] = ra.w;
            efv[4] = rb.x; efv[5] = rb.y; efv[6] = rb.z; efv[7] = rb.w;
        } else {
            uint4 r = ((const uint4*)ef)[eidx];
            efv[0] = bflo(r.x); efv[1] = bfhi(r.x);
            efv[2] = bflo(r.y); efv[3] = bfhi(r.y);
            efv[4] = bflo(r.z); efv[5] = bfhi(r.z);
            efv[6] = bflo(r.w); efv[7] = bfhi(r.w);
        }
#pragma unroll 1
        for (int d0 = 0; d0 < 64; d0 += 8) {
            float ev[8];
#pragma unroll
            for (int dd = 0; dd < 8; ++dd) {
                float a = be[d0 + dd];
#pragma unroll
                for (int k = 0; k < 8; ++k) a = fmaf(efv[k], We[k * 64 + d0 + dd], a);
                ev[dd] = fmaxf(a, 0.f);
            }
#pragma unroll
            for (int dd = 0; dd < 8; ++dd) {
                const float* w = Wm + (64 + d0 + dd) * 64;
#pragma unroll
                for (int c = 0; c < 64; ++c) acc[c] = fmaf(ev[dd], w[c], acc[c]);
            }
        }

        float* ag = agg + (size_t)d * 64;
#pragma unroll
        for (int c = 0; c < 64; ++c) unsafeAtomicAdd(&ag[c], fmaxf(acc[c], 0.f));
    }
}

// ---------------- update: h = relu([h, agg] @ Wu + bu) + h ----------------
__global__ __launch_bounds__(256) void update_kernel(
        const float* __restrict__ Wu, const float* __restrict__ bu,
        float* __restrict__ h, const float* __restrict__ agg, int N) {
    int i = blockIdx.x * blockDim.x + threadIdx.x;
    if (i >= N) return;
    float* hrow = h + (size_t)i * 64;
    const float4* h4 = (const float4*)hrow;
    const float4* a4 = (const float4*)(agg + (size_t)i * 64);
    float acc[64];
#pragma unroll
    for (int c = 0; c < 64; ++c) acc[c] = bu[c];
#pragma unroll 1
    for (int j0 = 0; j0 < 64; j0 += 8) {
        float4 xa = h4[j0 >> 2], xb = h4[(j0 >> 2) + 1];
        float x[8] = {xa.x, xa.y, xa.z, xa.w, xb.x, xb.y, xb.z, xb.w};
#pragma unroll
        for (int jj = 0; jj < 8; ++jj) {
            const float* w = Wu + (j0 + jj) * 64;
#pragma unroll
            for (int c = 0; c < 64; ++c) acc[c] = fmaf(x[jj], w[c], acc[c]);
        }
    }
#pragma unroll 1
    for (int j0 = 0; j0 < 64; j0 += 8) {
        float4 xa = a4[j0 >> 2], xb = a4[(j0 >> 2) + 1];
        float x[8] = {xa.x, xa.y, xa.z, xa.w, xb.x, xb.y, xb.z, xb.w};
#pragma unroll
        for (int jj = 0; jj < 8; ++jj) {
            const float* w = Wu + (64 + j0 + jj) * 64;
#pragma unroll
            for (int c = 0; c < 64; ++c) acc[c] = fmaf(x[jj], w[c], acc[c]);
        }
    }
#pragma unroll
    for (int c = 0; c < 64; ++c) {
        float old = hrow[c];
        hrow[c] = fmaxf(acc[c], 0.f) + old;
    }
}

// ---------------- scores: relu([h_s, h_d] @ Ws1 + bs1) @ Ws2 + bs2 ----------------
__global__ __launch_bounds__(256) void scores_kernel(
        const float* __restrict__ Ws1, const float* __restrict__ bs1,
        const float* __restrict__ Ws2, const float* __restrict__ bs2,
        const int* __restrict__ ods, const int* __restrict__ odd,
        const float* __restrict__ h, void* __restrict__ out, int P,
        const int* __restrict__ flagp) {
    int p = blockIdx.x * blockDim.x + threadIdx.x;
    if (p >= P) return;
    int s = ods[p], d = odd[p];
    float acc[64];
#pragma unroll
    for (int c = 0; c < 64; ++c) acc[c] = bs1[c];
    const float4* hs4 = (const float4*)(h + (size_t)s * 64);
    const float4* hd4 = (const float4*)(h + (size_t)d * 64);
#pragma unroll 1
    for (int j0 = 0; j0 < 64; j0 += 8) {
        float4 xa = hs4[j0 >> 2], xb = hs4[(j0 >> 2) + 1];
        float x[8] = {xa.x, xa.y, xa.z, xa.w, xb.x, xb.y, xb.z, xb.w};
#pragma unroll
        for (int jj = 0; jj < 8; ++jj) {
            const float* w = Ws1 + (j0 + jj) * 64;
#pragma unroll
            for (int c = 0; c < 64; ++c) acc[c] = fmaf(x[jj], w[c], acc[c]);
        }
    }
#pragma unroll 1
    for (int j0 = 0; j0 < 64; j0 += 8) {
        float4 xa = hd4[j0 >> 2], xb = hd4[(j0 >> 2) + 1];
        float x[8] = {xa.x, xa.y, xa.z, xa.w, xb.x, xb.y, xb.z, xb.w};
#pragma unroll
        for (int jj = 0; jj < 8; ++jj) {
            const float* w = Ws1 + (64 + j0 + jj) * 64;
#pragma unroll
            for (int c = 0; c < 64; ++c) acc[c] = fmaf(x[jj], w[c], acc[c]);
        }
    }
    float score = bs2[0];
#pragma unroll
    for (int c = 0; c < 64; ++c) score = fmaf(fmaxf(acc[c], 0.f), Ws2[c], score);
    if (*flagp) ((float*)out)[p] = score;
    else ((__hip_bfloat16*)out)[p] = __float2bfloat16(score);
}

// ---------------- graph embed: gsum[c] = sum_i h[i][c] ----------------
__global__ __launch_bounds__(256) void embed_kernel(
        const float* __restrict__ h, float* __restrict__ gsum, int N) {
    __shared__ float red[256];
    int c = threadIdx.x & 63;
    int sub = threadIdx.x >> 6;   // 0..3
    float a = 0.f;
    for (int i = blockIdx.x * 4 + sub; i < N; i += gridDim.x * 4)
        a += h[(size_t)i * 64 + c];
    red[threadIdx.x] = a;
    __syncthreads();
    if (threadIdx.x < 64) {
        float t = red[threadIdx.x] + red[threadIdx.x + 64] +
                  red[threadIdx.x + 128] + red[threadIdx.x + 192];
        unsafeAtomicAdd(&gsum[threadIdx.x], t);
    }
}

// ---------------- dynamic-K head (tiny) ----------------
__global__ void khead_kernel(const float* __restrict__ ws,
                             void* __restrict__ out, int N, int P,
                             const int* __restrict__ flagp) {
    if (threadIdx.x != 0 || blockIdx.x != 0) return;
    float x[68];
    float invN = 1.f / (float)N;
#pragma unroll
    for (int c = 0; c < 64; ++c) x[c] = ws[OFF_GSUM + c] * invN;
#pragma unroll
    for (int k = 0; k < 4; ++k) x[64 + k] = ws[OFF_TS + k];
    float h1[32];
    for (int j = 0; j < 32; ++j) {
        float a = ws[OFF_BK1 + j];
        for (int i = 0; i < 68; ++i) a = fmaf(x[i], ws[OFF_WK1 + i * 32 + j], a);
        h1[j] = fmaxf(a, 0.f);
    }
    float h2[16];
    for (int k2 = 0; k2 < 16; ++k2) {
        float a = ws[OFF_BK2 + k2];
        for (int j = 0; j < 32; ++j) a = fmaf(h1[j], ws[OFF_WK2 + j * 16 + k2], a);
        h2[k2] = fmaxf(a, 0.f);
    }
    float raw = ws[OFF_BK3];
    for (int k2 = 0; k2 < 16; ++k2) raw = fmaf(h2[k2], ws[OFF_WK3 + k2], raw);
    float sig = 1.f / (1.f + expf(-raw));
    float k = 1.f + 49.f * sig;
    if (*flagp) ((float*)out)[P] = k;
    else ((__hip_bfloat16*)out)[P] = __float2bfloat16(k);
}

extern "C" void kernel_launch(void* const* d_in, const int* in_sizes, int n_in,
                              void* d_out, int out_size, void* d_ws, size_t ws_size,
                              hipStream_t stream) {
    const void* nf = d_in[0];
    const int*  ei = (const int*)d_in[1];
    const void* ef = d_in[2];
    const int*  od = (const int*)d_in[3];
    float* ws = (float*)d_ws;

    const int N = in_sizes[0] / 16;   // 50000
    const int E = in_sizes[1] / 2;    // 1200000
    const int P = in_sizes[3] / 2;    // 10000

    float* h    = ws + OFF_H;
    float* agg  = h + (size_t)N * 64;
    int*   flag = (int*)(ws + OFF_FLAG);

    // 0. detect whether float data is f32 (reference dtype) or bf16 (converted)
    detect_dtype_kernel<<<1, 64, 0, stream>>>((const unsigned short*)nf, flag);

    // 1. convert all weights (+ traffic stats) to f32 in ws
    ConvArgs ca;
    const int srcidx[19] = {5, 6, 7, 8, 9, 10, 11, 12, 13, 14, 15, 16, 17, 18, 19, 20, 21, 22, 4};
    const int wsoff[19]  = {OFF_WN, OFF_BN, OFF_WE, OFF_BE, OFF_WM, OFF_BM, OFF_WU, OFF_BU,
                            OFF_WS1, OFF_BS1, OFF_WS2, OFF_BS2, OFF_WK1, OFF_BK1, OFF_WK2,
                            OFF_BK2, OFF_WK3, OFF_BK3, OFF_TS};
    int maxn = 0;
    for (int i = 0; i < 19; ++i) {
        ca.src[i] = d_in[srcidx[i]];
        ca.off[i] = wsoff[i];
        ca.n[i]   = in_sizes[srcidx[i]];
        if (ca.n[i] > maxn) maxn = ca.n[i];
    }
    dim3 cgrid((maxn + 255) / 256, 19);
    convert_all_kernel<<<cgrid, 256, 0, stream>>>(ca, ws, flag);

    // 2. node projection
    node_proj_kernel<<<(N * 64 + 255) / 256, 256, 0, stream>>>(nf, ws, h, N, flag);

    // 3. GNN layers
    for (int l = 0; l < 3; ++l) {
        hipMemsetAsync(agg, 0, (size_t)N * 64 * sizeof(float), stream);
        msg_kernel<<<(E + 255) / 256, 256, 0, stream>>>(
            ws + OFF_WM + l * 8192, ws + OFF_BM + l * 64,
            ws + OFF_WE, ws + OFF_BE, ef, ei, ei + E, h, agg, E, flag);
        update_kernel<<<(N + 255) / 256, 256, 0, stream>>>(
            ws + OFF_WU + l * 8192, ws + OFF_BU + l * 64, h, agg, N);
    }

    // 4. per-flow scores
    scores_kernel<<<(P + 255) / 256, 256, 0, stream>>>(
        ws + OFF_WS1, ws + OFF_BS1, ws + OFF_WS2, ws + OFF_BS2,
        od, od + P, h, d_out, P, flag);

    // 5. graph embedding + dynamic-K head
    hipMemsetAsync(ws + OFF_GSUM, 0, 64 * sizeof(float), stream);
    embed_kernel<<<256, 256, 0, stream>>>(h, ws + OFF_GSUM, N);
    khead_kernel<<<1, 64, 0, stream>>>(ws, d_out, N, P, flag);
}

// Round 3
// 2583.332 us; speedup vs baseline: 4.8332x; 4.8332x over previous
//
#include <hip/hip_runtime.h>
#include <hip/hip_bf16.h>

// ---------------- workspace layout (float offsets, fixed small region) ----------------
#define OFF_WN   0
#define OFF_BN   1024
#define OFF_WE   1088
#define OFF_BE   1600
#define OFF_WM   1664            // 3 * 128 * 64
#define OFF_BM   26240           // 3 * 64
#define OFF_WU   26432           // 3 * 128 * 64
#define OFF_BU   51008           // 3 * 64
#define OFF_WS1  51200           // 128 * 64
#define OFF_BS1  59392
#define OFF_WS2  59456
#define OFF_BS2  59520
#define OFF_WK1  59521           // 68 * 32
#define OFF_BK1  61697
#define OFF_WK2  61729           // 32 * 16
#define OFF_BK2  62241
#define OFF_WK3  62257
#define OFF_BK3  62273
#define OFF_TS   62274           // traffic stats (4)
#define OFF_GSUM 62278           // graph-embed accumulator (64)
#define OFF_FLAG 62344           // dtype flag: 1 = inputs are f32, 0 = bf16
#define OFF_H    65536           // big arrays start here (see kernel_launch)

__device__ __forceinline__ float bf2f(unsigned short u) {
    unsigned int i = ((unsigned int)u) << 16;
    float f;
    __builtin_memcpy(&f, &i, sizeof(f));
    return f;
}
__device__ __forceinline__ float bflo(unsigned int u) {
    unsigned int i = u << 16;
    float f; __builtin_memcpy(&f, &i, sizeof(f)); return f;
}
__device__ __forceinline__ float bfhi(unsigned int u) {
    unsigned int i = u & 0xffff0000u;
    float f; __builtin_memcpy(&f, &i, sizeof(f)); return f;
}

// ---------------- dtype sniffer (R2 evidence: takes the f32 branch) ----------------
__global__ void detect_dtype_kernel(const unsigned short* __restrict__ nf,
                                    int* __restrict__ flag) {
    int t = threadIdx.x;  // 64 threads
    float m = 0.f;
    for (int i = t; i < 1024; i += 64) {
        float v = fabsf(bf2f(nf[i]));
        if (!isnan(v)) m = fmaxf(m, v);
        else m = 1e30f;
    }
    for (int o = 32; o > 0; o >>= 1) m = fmaxf(m, __shfl_down(m, o));
    if (t == 0) flag[0] = (m > 1e6f) ? 1 : 0;
}

// ---------------- weight conversion ----------------
struct ConvArgs {
    const void* src[19];
    int off[19];
    int n[19];
};

__global__ __launch_bounds__(256) void convert_all_kernel(
        ConvArgs a, float* __restrict__ ws, const int* __restrict__ flagp) {
    int isf32 = *flagp;
    int ai = blockIdx.y;
    int i  = blockIdx.x * blockDim.x + threadIdx.x;
    if (i < a.n[ai]) {
        float v = isf32 ? ((const float*)a.src[ai])[i]
                        : bf2f(((const unsigned short*)a.src[ai])[i]);
        ws[a.off[ai] + i] = v;
    }
}

// ---------------- node projection: h = relu(nf @ Wn + bn) ----------------
__global__ __launch_bounds__(256) void node_proj_kernel(
        const void* __restrict__ nf, const float* __restrict__ ws,
        float* __restrict__ h, int N, const int* __restrict__ flagp) {
    int idx = blockIdx.x * blockDim.x + threadIdx.x;
    if (idx >= N * 64) return;
    int isf32 = *flagp;
    int i = idx >> 6, c = idx & 63;
    const float* Wn = ws + OFF_WN;
    float acc = ws[OFF_BN + c];
    float x[16];
    if (isf32) {
        const float* row = (const float*)nf + (size_t)i * 16;
#pragma unroll
        for (int k = 0; k < 16; ++k) x[k] = row[k];
    } else {
        const unsigned short* row = (const unsigned short*)nf + (size_t)i * 16;
#pragma unroll
        for (int k = 0; k < 16; ++k) x[k] = bf2f(row[k]);
    }
#pragma unroll
    for (int k = 0; k < 16; ++k) acc = fmaf(x[k], Wn[k * 64 + c], acc);
    h[idx] = fmaxf(acc, 0.f);
}

// ---------------- CSR build ----------------
__global__ __launch_bounds__(256) void count_kernel(
        const int* __restrict__ dst, int* __restrict__ deg, int E) {
    int e = blockIdx.x * blockDim.x + threadIdx.x;
    if (e < E) atomicAdd(&deg[dst[e]], 1);
}

// single-block scan: off[i] = exclusive prefix of deg, off[N] = E; cursor = copy of off
__global__ __launch_bounds__(1024) void scan_kernel(
        const int* __restrict__ deg, int* __restrict__ off,
        int* __restrict__ cursor, int N) {
    __shared__ int sh[1024];
    __shared__ int carry_sh;
    int tid = threadIdx.x;
    if (tid == 0) carry_sh = 0;
    __syncthreads();
    for (int base = 0; base < N; base += 1024) {
        int i = base + tid;
        int v = (i < N) ? deg[i] : 0;
        sh[tid] = v;
        __syncthreads();
        for (int o = 1; o < 1024; o <<= 1) {
            int t = (tid >= o) ? sh[tid - o] : 0;
            __syncthreads();
            sh[tid] += t;
            __syncthreads();
        }
        int incl = sh[tid];
        int carry = carry_sh;
        if (i < N) {
            int ex = carry + incl - v;
            off[i] = ex;
            cursor[i] = ex;
        }
        __syncthreads();
        if (tid == 1023) carry_sh = carry + incl;
        __syncthreads();
    }
    if (tid == 0) off[N] = carry_sh;
}

__global__ __launch_bounds__(256) void fill_kernel(
        const int* __restrict__ dst, int* __restrict__ cursor,
        int* __restrict__ eid, int E) {
    int e = blockIdx.x * blockDim.x + threadIdx.x;
    if (e < E) {
        int pos = atomicAdd(&cursor[dst[e]], 1);
        eid[pos] = e;
    }
}

// ---------------- per-layer node transform: A[n] = h[n] @ Wm1 + bm ----------------
__global__ __launch_bounds__(256) void nodeA_kernel(
        const float* __restrict__ Wm1, const float* __restrict__ bm,
        const float* __restrict__ h, float* __restrict__ A, int N) {
    int i = blockIdx.x * blockDim.x + threadIdx.x;
    if (i >= N) return;
    const float4* h4 = (const float4*)(h + (size_t)i * 64);
    float acc[64];
#pragma unroll
    for (int c = 0; c < 64; ++c) acc[c] = bm[c];
#pragma unroll 1
    for (int j0 = 0; j0 < 64; j0 += 8) {
        float4 xa = h4[j0 >> 2], xb = h4[(j0 >> 2) + 1];
        float x[8] = {xa.x, xa.y, xa.z, xa.w, xb.x, xb.y, xb.z, xb.w};
#pragma unroll
        for (int jj = 0; jj < 8; ++jj) {
            const float* w = Wm1 + (j0 + jj) * 64;
#pragma unroll
            for (int c = 0; c < 64; ++c) acc[c] = fmaf(x[jj], w[c], acc[c]);
        }
    }
    float4* o4 = (float4*)(A + (size_t)i * 64);
#pragma unroll
    for (int c = 0; c < 16; ++c)
        o4[c] = make_float4(acc[4 * c], acc[4 * c + 1], acc[4 * c + 2], acc[4 * c + 3]);
}

// ---------------- gather: agg[n] = sum_{e: dst=n} relu(A[src_e] + edge_mlp(ef_e)) ----------------
__global__ __launch_bounds__(256) void gather_msg_kernel(
        const float* __restrict__ Wm2, const float* __restrict__ We,
        const float* __restrict__ be, const void* __restrict__ ef,
        const int* __restrict__ src, const int* __restrict__ eid,
        const int* __restrict__ off, const float* __restrict__ A,
        float* __restrict__ agg, int N, const int* __restrict__ flagp) {
    int i = blockIdx.x * blockDim.x + threadIdx.x;
    if (i >= N) return;
    int isf32 = *flagp;
    int k0 = off[i], k1 = off[i + 1];
    float acc[64];
#pragma unroll
    for (int c = 0; c < 64; ++c) acc[c] = 0.f;

    for (int k = k0; k < k1; ++k) {
        int e = eid[k];
        int s = src[e];
        // t = A[src]  (bm already folded in)
        const float4* a4 = (const float4*)(A + (size_t)s * 64);
        float t[64];
#pragma unroll
        for (int c = 0; c < 16; ++c) {
            float4 v = a4[c];
            t[4 * c] = v.x; t[4 * c + 1] = v.y; t[4 * c + 2] = v.z; t[4 * c + 3] = v.w;
        }
        // edge features
        float efv[8];
        if (isf32) {
            const float4* e4 = (const float4*)ef + (size_t)e * 2;
            float4 ra = e4[0], rb = e4[1];
            efv[0] = ra.x; efv[1] = ra.y; efv[2] = ra.z; efv[3] = ra.w;
            efv[4] = rb.x; efv[5] = rb.y; efv[6] = rb.z; efv[7] = rb.w;
        } else {
            uint4 r = ((const uint4*)ef)[e];
            efv[0] = bflo(r.x); efv[1] = bfhi(r.x);
            efv[2] = bflo(r.y); efv[3] = bfhi(r.y);
            efv[4] = bflo(r.z); efv[5] = bfhi(r.z);
            efv[6] = bflo(r.w); efv[7] = bfhi(r.w);
        }
        // t += relu(ef @ We + be) @ Wm2
#pragma unroll 1
        for (int d0 = 0; d0 < 64; d0 += 8) {
            float ev[8];
#pragma unroll
            for (int dd = 0; dd < 8; ++dd) {
                float a = be[d0 + dd];
#pragma unroll
                for (int kk = 0; kk < 8; ++kk) a = fmaf(efv[kk], We[kk * 64 + d0 + dd], a);
                ev[dd] = fmaxf(a, 0.f);
            }
#pragma unroll
            for (int dd = 0; dd < 8; ++dd) {
                const float* w = Wm2 + (d0 + dd) * 64;
#pragma unroll
                for (int c = 0; c < 64; ++c) t[c] = fmaf(ev[dd], w[c], t[c]);
            }
        }
#pragma unroll
        for (int c = 0; c < 64; ++c) acc[c] += fmaxf(t[c], 0.f);
    }

    float4* o4 = (float4*)(agg + (size_t)i * 64);
#pragma unroll
    for (int c = 0; c < 16; ++c)
        o4[c] = make_float4(acc[4 * c], acc[4 * c + 1], acc[4 * c + 2], acc[4 * c + 3]);
}

// ---------------- update: h = relu([h, agg] @ Wu + bu) + h ----------------
__global__ __launch_bounds__(256) void update_kernel(
        const float* __restrict__ Wu, const float* __restrict__ bu,
        float* __restrict__ h, const float* __restrict__ agg, int N) {
    int i = blockIdx.x * blockDim.x + threadIdx.x;
    if (i >= N) return;
    float* hrow = h + (size_t)i * 64;
    const float4* h4 = (const float4*)hrow;
    const float4* a4 = (const float4*)(agg + (size_t)i * 64);
    float acc[64];
#pragma unroll
    for (int c = 0; c < 64; ++c) acc[c] = bu[c];
#pragma unroll 1
    for (int j0 = 0; j0 < 64; j0 += 8) {
        float4 xa = h4[j0 >> 2], xb = h4[(j0 >> 2) + 1];
        float x[8] = {xa.x, xa.y, xa.z, xa.w, xb.x, xb.y, xb.z, xb.w};
#pragma unroll
        for (int jj = 0; jj < 8; ++jj) {
            const float* w = Wu + (j0 + jj) * 64;
#pragma unroll
            for (int c = 0; c < 64; ++c) acc[c] = fmaf(x[jj], w[c], acc[c]);
        }
    }
#pragma unroll 1
    for (int j0 = 0; j0 < 64; j0 += 8) {
        float4 xa = a4[j0 >> 2], xb = a4[(j0 >> 2) + 1];
        float x[8] = {xa.x, xa.y, xa.z, xa.w, xb.x, xb.y, xb.z, xb.w};
#pragma unroll
        for (int jj = 0; jj < 8; ++jj) {
            const float* w = Wu + (64 + j0 + jj) * 64;
#pragma unroll
            for (int c = 0; c < 64; ++c) acc[c] = fmaf(x[jj], w[c], acc[c]);
        }
    }
#pragma unroll
    for (int c = 0; c < 64; ++c) {
        float old = hrow[c];
        hrow[c] = fmaxf(acc[c], 0.f) + old;
    }
}

// ---------------- scores ----------------
__global__ __launch_bounds__(256) void scores_kernel(
        const float* __restrict__ Ws1, const float* __restrict__ bs1,
        const float* __restrict__ Ws2, const float* __restrict__ bs2,
        const int* __restrict__ ods, const int* __restrict__ odd,
        const float* __restrict__ h, void* __restrict__ out, int P,
        const int* __restrict__ flagp) {
    int p = blockIdx.x * blockDim.x + threadIdx.x;
    if (p >= P) return;
    int s = ods[p], d = odd[p];
    float acc[64];
#pragma unroll
    for (int c = 0; c < 64; ++c) acc[c] = bs1[c];
    const float4* hs4 = (const float4*)(h + (size_t)s * 64);
    const float4* hd4 = (const float4*)(h + (size_t)d * 64);
#pragma unroll 1
    for (int j0 = 0; j0 < 64; j0 += 8) {
        float4 xa = hs4[j0 >> 2], xb = hs4[(j0 >> 2) + 1];
        float x[8] = {xa.x, xa.y, xa.z, xa.w, xb.x, xb.y, xb.z, xb.w};
#pragma unroll
        for (int jj = 0; jj < 8; ++jj) {
            const float* w = Ws1 + (j0 + jj) * 64;
#pragma unroll
            for (int c = 0; c < 64; ++c) acc[c] = fmaf(x[jj], w[c], acc[c]);
        }
    }
#pragma unroll 1
    for (int j0 = 0; j0 < 64; j0 += 8) {
        float4 xa = hd4[j0 >> 2], xb = hd4[(j0 >> 2) + 1];
        float x[8] = {xa.x, xa.y, xa.z, xa.w, xb.x, xb.y, xb.z, xb.w};
#pragma unroll
        for (int jj = 0; jj < 8; ++jj) {
            const float* w = Ws1 + (64 + j0 + jj) * 64;
#pragma unroll
            for (int c = 0; c < 64; ++c) acc[c] = fmaf(x[jj], w[c], acc[c]);
        }
    }
    float score = bs2[0];
#pragma unroll
    for (int c = 0; c < 64; ++c) score = fmaf(fmaxf(acc[c], 0.f), Ws2[c], score);
    if (*flagp) ((float*)out)[p] = score;
    else ((__hip_bfloat16*)out)[p] = __float2bfloat16(score);
}

// ---------------- graph embed ----------------
__global__ __launch_bounds__(256) void embed_kernel(
        const float* __restrict__ h, float* __restrict__ gsum, int N) {
    __shared__ float red[256];
    int c = threadIdx.x & 63;
    int sub = threadIdx.x >> 6;   // 0..3
    float a = 0.f;
    for (int i = blockIdx.x * 4 + sub; i < N; i += gridDim.x * 4)
        a += h[(size_t)i * 64 + c];
    red[threadIdx.x] = a;
    __syncthreads();
    if (threadIdx.x < 64) {
        float t = red[threadIdx.x] + red[threadIdx.x + 64] +
                  red[threadIdx.x + 128] + red[threadIdx.x + 192];
        unsafeAtomicAdd(&gsum[threadIdx.x], t);
    }
}

// ---------------- dynamic-K head ----------------
__global__ void khead_kernel(const float* __restrict__ ws,
                             void* __restrict__ out, int N, int P,
                             const int* __restrict__ flagp) {
    if (threadIdx.x != 0 || blockIdx.x != 0) return;
    float x[68];
    float invN = 1.f / (float)N;
#pragma unroll
    for (int c = 0; c < 64; ++c) x[c] = ws[OFF_GSUM + c] * invN;
#pragma unroll
    for (int k = 0; k < 4; ++k) x[64 + k] = ws[OFF_TS + k];
    float h1[32];
    for (int j = 0; j < 32; ++j) {
        float a = ws[OFF_BK1 + j];
        for (int i = 0; i < 68; ++i) a = fmaf(x[i], ws[OFF_WK1 + i * 32 + j], a);
        h1[j] = fmaxf(a, 0.f);
    }
    float h2[16];
    for (int k2 = 0; k2 < 16; ++k2) {
        float a = ws[OFF_BK2 + k2];
        for (int j = 0; j < 32; ++j) a = fmaf(h1[j], ws[OFF_WK2 + j * 16 + k2], a);
        h2[k2] = fmaxf(a, 0.f);
    }
    float raw = ws[OFF_BK3];
    for (int k2 = 0; k2 < 16; ++k2) raw = fmaf(h2[k2], ws[OFF_WK3 + k2], raw);
    float sig = 1.f / (1.f + expf(-raw));
    float k = 1.f + 49.f * sig;
    if (*flagp) ((float*)out)[P] = k;
    else ((__hip_bfloat16*)out)[P] = __float2bfloat16(k);
}

extern "C" void kernel_launch(void* const* d_in, const int* in_sizes, int n_in,
                              void* d_out, int out_size, void* d_ws, size_t ws_size,
                              hipStream_t stream) {
    const void* nf = d_in[0];
    const int*  ei = (const int*)d_in[1];
    const void* ef = d_in[2];
    const int*  od = (const int*)d_in[3];
    float* ws = (float*)d_ws;

    const int N = in_sizes[0] / 16;   // 50000
    const int E = in_sizes[1] / 2;    // 1200000
    const int P = in_sizes[3] / 2;    // 10000

    // big-array layout: h, agg, A (N*64 f32 each), then CSR ints
    float* h      = ws + OFF_H;
    float* agg    = h + (size_t)N * 64;
    float* A      = agg + (size_t)N * 64;
    int*   deg    = (int*)(A + (size_t)N * 64);
    int*   off    = deg + N;          // N+1 entries
    int*   cursor = off + N + 1;
    int*   eid    = cursor + N;       // E entries
    int*   flag   = (int*)(ws + OFF_FLAG);

    const int* srcv = ei;
    const int* dstv = ei + E;

    // 0. dtype detect
    detect_dtype_kernel<<<1, 64, 0, stream>>>((const unsigned short*)nf, flag);

    // 1. convert weights to f32 in ws
    ConvArgs ca;
    const int srcidx[19] = {5, 6, 7, 8, 9, 10, 11, 12, 13, 14, 15, 16, 17, 18, 19, 20, 21, 22, 4};
    const int wsoff[19]  = {OFF_WN, OFF_BN, OFF_WE, OFF_BE, OFF_WM, OFF_BM, OFF_WU, OFF_BU,
                            OFF_WS1, OFF_BS1, OFF_WS2, OFF_BS2, OFF_WK1, OFF_BK1, OFF_WK2,
                            OFF_BK2, OFF_WK3, OFF_BK3, OFF_TS};
    int maxn = 0;
    for (int i = 0; i < 19; ++i) {
        ca.src[i] = d_in[srcidx[i]];
        ca.off[i] = wsoff[i];
        ca.n[i]   = in_sizes[srcidx[i]];
        if (ca.n[i] > maxn) maxn = ca.n[i];
    }
    dim3 cgrid((maxn + 255) / 256, 19);
    convert_all_kernel<<<cgrid, 256, 0, stream>>>(ca, ws, flag);

    // 2. node projection
    node_proj_kernel<<<(N * 64 + 255) / 256, 256, 0, stream>>>(nf, ws, h, N, flag);

    // 3. build CSR by dst (once; reused by all 3 layers)
    hipMemsetAsync(deg, 0, (size_t)N * sizeof(int), stream);
    count_kernel<<<(E + 255) / 256, 256, 0, stream>>>(dstv, deg, E);
    scan_kernel<<<1, 1024, 0, stream>>>(deg, off, cursor, N);
    fill_kernel<<<(E + 255) / 256, 256, 0, stream>>>(dstv, cursor, eid, E);

    // 4. GNN layers: nodeA -> gather (no atomics, no agg memset) -> update
    for (int l = 0; l < 3; ++l) {
        const float* Wm1 = ws + OFF_WM + l * 8192;        // rows 0..63
        const float* Wm2 = Wm1 + 64 * 64;                 // rows 64..127
        nodeA_kernel<<<(N + 255) / 256, 256, 0, stream>>>(
            Wm1, ws + OFF_BM + l * 64, h, A, N);
        gather_msg_kernel<<<(N + 255) / 256, 256, 0, stream>>>(
            Wm2, ws + OFF_WE, ws + OFF_BE, ef, srcv, eid, off, A, agg, N, flag);
        update_kernel<<<(N + 255) / 256, 256, 0, stream>>>(
            ws + OFF_WU + l * 8192, ws + OFF_BU + l * 64, h, agg, N);
    }

    // 5. per-flow scores
    scores_kernel<<<(P + 255) / 256, 256, 0, stream>>>(
        ws + OFF_WS1, ws + OFF_BS1, ws + OFF_WS2, ws + OFF_BS2,
        od, od + P, h, d_out, P, flag);

    // 6. graph embedding + dynamic-K head
    hipMemsetAsync(ws + OFF_GSUM, 0, 64 * sizeof(float), stream);
    embed_kernel<<<256, 256, 0, stream>>>(h, ws + OFF_GSUM, N);
    khead_kernel<<<1, 64, 0, stream>>>(ws, d_out, N, P, flag);
}